// Round 1
// baseline (285.446 us; speedup 1.0000x reference)
//
#include <hip/hip_runtime.h>
#include <hip/hip_bf16.h>

#define B_ 2
#define T_ 4096
#define C_ 512
#define P_ 64
#define PS_ 16
#define CS_ 5
#define MB_ 128
#define FD_ 128

// ---------------- Kernel A: bm = y @ W_proj2  (8192x512)@(512x128) ----------
// tile: 32 rows x 128 cols, 256 threads, c staged in LDS chunks of 64
__global__ __launch_bounds__(256) void k_bm(const float* __restrict__ y,
                                            const float* __restrict__ W,
                                            float* __restrict__ bm) {
  __shared__ __align__(16) float ys[32*64];
  const int tid = threadIdx.x;
  const int row0 = blockIdx.x * 32;
  const int tn = tid & 63;
  const int tm = tid >> 6;   // 0..3 -> 8 rows each
  float acc0[8], acc1[8];
  #pragma unroll
  for (int r = 0; r < 8; r++) { acc0[r] = 0.f; acc1[r] = 0.f; }
  for (int cc = 0; cc < C_; cc += 64) {
    __syncthreads();
    #pragma unroll
    for (int j = 0; j < 2; j++) {
      int id = tid + j*256;      // 0..511
      int r  = id >> 4;          // 0..31
      int c4 = id & 15;
      *(float4*)&ys[r*64 + c4*4] =
          *(const float4*)&y[(size_t)(row0 + r)*C_ + cc + c4*4];
    }
    __syncthreads();
    #pragma unroll
    for (int c4 = 0; c4 < 16; c4++) {
      const int c = cc + c4*4;
      const float w00 = W[(c+0)*MB_+tn],    w01 = W[(c+1)*MB_+tn],
                  w02 = W[(c+2)*MB_+tn],    w03 = W[(c+3)*MB_+tn];
      const float w10 = W[(c+0)*MB_+tn+64], w11 = W[(c+1)*MB_+tn+64],
                  w12 = W[(c+2)*MB_+tn+64], w13 = W[(c+3)*MB_+tn+64];
      #pragma unroll
      for (int r = 0; r < 8; r++) {
        float4 v = *(float4*)&ys[(tm*8 + r)*64 + c4*4];
        acc0[r] = fmaf(v.x,w00, fmaf(v.y,w01, fmaf(v.z,w02, fmaf(v.w,w03, acc0[r]))));
        acc1[r] = fmaf(v.x,w10, fmaf(v.y,w11, fmaf(v.z,w12, fmaf(v.w,w13, acc1[r]))));
      }
    }
  }
  #pragma unroll
  for (int r = 0; r < 8; r++) {
    const size_t row = (size_t)(row0 + tm*8 + r);
    bm[row*MB_ + tn]      = acc0[r];
    bm[row*MB_ + tn + 64] = acc1[r];
  }
}

// ---------------- Kernel B: yc = y @ W_proj_comp, stored bf16 ---------------
__global__ __launch_bounds__(256) void k_yc(const float* __restrict__ y,
                                            const float* __restrict__ Wc,
                                            __hip_bfloat16* __restrict__ yc) {
  const int id = blockIdx.x*256 + threadIdx.x;
  if (id >= B_*T_*CS_) return;
  const int bt = id / CS_;
  const int k  = id % CS_;
  const float4* yv = (const float4*)(y + (size_t)bt*C_);
  float acc = 0.f;
  for (int c4 = 0; c4 < C_/4; c4++) {
    float4 v = yv[c4];
    const float* w = &Wc[(c4*4)*CS_ + k];
    acc = fmaf(v.x, w[0],      acc);
    acc = fmaf(v.y, w[CS_],    acc);
    acc = fmaf(v.z, w[2*CS_],  acc);
    acc = fmaf(v.w, w[3*CS_],  acc);
  }
  yc[id] = __float2bfloat16(acc);
}

// ------- Kernel C: per (b,t): res -> mix -> out (gathers), 32 t per block ---
#define TT 32
__global__ __launch_bounds__(256) void k_mid(const __hip_bfloat16* __restrict__ yc,
                                             const float* __restrict__ bm,
                                             const float* __restrict__ WB,
                                             const float* __restrict__ Wbias,
                                             const float* __restrict__ Wps1,
                                             const int* __restrict__ patches,
                                             const int* __restrict__ pproj,
                                             float* __restrict__ obm) {
  __shared__ __align__(16) __hip_bfloat16 yc_s[T_*CS_];  // 40KB
  __shared__ __align__(16) int patch_s[P_*PS_];          // 4KB
  __shared__ int   pp_s[P_];
  __shared__ float res_s[P_];
  __shared__ float mix_s[P_];
  __shared__ float outp_s[2*MB_];
  const int tid = threadIdx.x;
  const int b   = blockIdx.x >> 7;           // grid 256: 128 chunks x 2 batches
  const int t0  = (blockIdx.x & 127) * TT;

  // stage yc slab for this batch: 40KB = 2560 uint4
  {
    const uint4* src = (const uint4*)(yc + (size_t)b*T_*CS_);
    uint4* dst = (uint4*)yc_s;
    for (int j = tid; j < (T_*CS_*2)/16; j += 256) dst[j] = src[j];
  }
  __syncthreads();

  const float* bmb = bm + (size_t)b*T_*MB_;
  for (int tt = 0; tt < TT; tt++) {
    const int t = t0 + tt;
    // stage patches row (1024 ints = 256 int4) + pproj row (64 ints)
    ((int4*)patch_s)[tid] = ((const int4*)(patches + (size_t)t*P_*PS_))[tid];
    if (tid < P_) pp_s[tid] = pproj[(size_t)t*P_ + tid];
    __syncthreads();

    // res[p] = sum_{s,c} yc[b, patches[t,p,s], c] * WB[p,s,c] + bias[p]
    {
      const int p = tid >> 2, part = tid & 3;
      float sum = 0.f;
      #pragma unroll
      for (int ss = 0; ss < 4; ss++) {
        const int s   = part*4 + ss;
        const int idx = patch_s[p*PS_ + s];
        const float* wb = &WB[p*PS_*CS_ + s*CS_];
        #pragma unroll
        for (int c = 0; c < CS_; c++)
          sum = fmaf(__bfloat162float(yc_s[idx*CS_ + c]), wb[c], sum);
      }
      sum += __shfl_xor(sum, 1);
      sum += __shfl_xor(sum, 2);
      if (part == 0) res_s[p] = sum + Wbias[p];
    }
    __syncthreads();

    // mix[q] = sum_p res[p] * Wps1[p][q]
    if (tid < P_) {
      float acc = 0.f;
      #pragma unroll 8
      for (int p = 0; p < P_; p++) acc = fmaf(res_s[p], Wps1[p*P_ + tid], acc);
      mix_s[tid] = acc;
    }
    __syncthreads();

    // out[m] = sum_p mix[p] * bm[b, pp[t,p], m]
    {
      const int m = tid & 127, half = tid >> 7;
      float acc = 0.f;
      #pragma unroll 8
      for (int p = half*32; p < half*32 + 32; p++)
        acc = fmaf(mix_s[p], bmb[(size_t)pp_s[p]*MB_ + m], acc);
      outp_s[half*MB_ + m] = acc;
    }
    __syncthreads();
    if (tid < MB_)
      obm[((size_t)b*T_ + t)*MB_ + tid] = outp_s[tid] + outp_s[MB_ + tid];
    __syncthreads();
  }
}

// ---------------- Kernel D: final = obm @ W_FINAL (8192x128)@(128x128) ------
__global__ __launch_bounds__(256) void k_final(const float* __restrict__ obm,
                                               const float* __restrict__ WF,
                                               float* __restrict__ outp) {
  __shared__ __align__(16) float os[32*MB_];  // 16KB
  const int tid = threadIdx.x;
  const int row0 = blockIdx.x * 32;
  {
    const float4* src = (const float4*)(obm + (size_t)row0*MB_);
    float4* dst = (float4*)os;
    for (int j = tid; j < 32*MB_/4; j += 256) dst[j] = src[j];
  }
  __syncthreads();
  const int tn = tid & 63, tm = tid >> 6;
  float acc0[8], acc1[8];
  #pragma unroll
  for (int r = 0; r < 8; r++) { acc0[r] = 0.f; acc1[r] = 0.f; }
  #pragma unroll
  for (int m4 = 0; m4 < MB_/4; m4++) {
    const int m = m4*4;
    const float w00 = WF[(m+0)*FD_+tn],    w01 = WF[(m+1)*FD_+tn],
                w02 = WF[(m+2)*FD_+tn],    w03 = WF[(m+3)*FD_+tn];
    const float w10 = WF[(m+0)*FD_+tn+64], w11 = WF[(m+1)*FD_+tn+64],
                w12 = WF[(m+2)*FD_+tn+64], w13 = WF[(m+3)*FD_+tn+64];
    #pragma unroll
    for (int r = 0; r < 8; r++) {
      float4 v = *(float4*)&os[(tm*8 + r)*MB_ + m];
      acc0[r] = fmaf(v.x,w00, fmaf(v.y,w01, fmaf(v.z,w02, fmaf(v.w,w03, acc0[r]))));
      acc1[r] = fmaf(v.x,w10, fmaf(v.y,w11, fmaf(v.z,w12, fmaf(v.w,w13, acc1[r]))));
    }
  }
  #pragma unroll
  for (int r = 0; r < 8; r++) {
    const size_t row = (size_t)(row0 + tm*8 + r);
    outp[row*FD_ + tn]      = acc0[r];
    outp[row*FD_ + tn + 64] = acc1[r];
  }
}

extern "C" void kernel_launch(void* const* d_in, const int* in_sizes, int n_in,
                              void* d_out, int out_size, void* d_ws, size_t ws_size,
                              hipStream_t stream) {
  const float* y     = (const float*)d_in[0];
  const float* WB    = (const float*)d_in[1];
  const float* Wbias = (const float*)d_in[2];
  const float* Wp2   = (const float*)d_in[3];
  const float* Wpc   = (const float*)d_in[4];
  const float* Wps1  = (const float*)d_in[5];
  const float* WF    = (const float*)d_in[6];
  const int* patches = (const int*)d_in[7];
  const int* pproj   = (const int*)d_in[8];
  float* out = (float*)d_out;

  char* ws = (char*)d_ws;
  float* bm            = (float*)(ws);                          // 4,194,304 B
  __hip_bfloat16* yc   = (__hip_bfloat16*)(ws + 4194304);       //    81,920 B
  float* obm           = (float*)(ws + 4194304 + 81920);        // 4,194,304 B

  k_bm   <<<dim3((B_*T_)/32), dim3(256), 0, stream>>>(y, Wp2, bm);
  k_yc   <<<dim3((B_*T_*CS_ + 255)/256), dim3(256), 0, stream>>>(y, Wpc, yc);
  k_mid  <<<dim3(B_*(T_/TT)), dim3(256), 0, stream>>>(yc, bm, WB, Wbias, Wps1,
                                                      patches, pproj, obm);
  k_final<<<dim3((B_*T_)/32), dim3(256), 0, stream>>>(obm, WF, out);
}

// Round 2
// 183.973 us; speedup vs baseline: 1.5516x; 1.5516x over previous
//
#include <hip/hip_runtime.h>
#include <hip/hip_bf16.h>

#define B_ 2
#define T_ 4096
#define C_ 512
#define P_ 64
#define PS_ 16
#define CS_ 5
#define MB_ 128
#define FD_ 128

__device__ __forceinline__ float bf_lo(unsigned u) {
  return __uint_as_float(u << 16);
}
__device__ __forceinline__ float bf_hi(unsigned u) {
  return __uint_as_float(u & 0xffff0000u);
}
__device__ __forceinline__ float rdlane_f(float v, int p) {
  return __uint_as_float((unsigned)__builtin_amdgcn_readlane((int)__float_as_uint(v), p));
}

// ---- k_prep: yc_pad[b*T+t][8] bf16 = (y @ W_proj_comp) padded rows --------
// wave-per-row; Wc slice (40 floats) register-resident per lane.
__global__ __launch_bounds__(256) void k_prep(const float* __restrict__ y,
                                              const float* __restrict__ Wc,
                                              __hip_bfloat16* __restrict__ ycp) {
  const int lane = threadIdx.x & 63;
  const int wid  = threadIdx.x >> 6;
  float wc[40];
  {
    const float4* src = (const float4*)(Wc + lane * 40);
    #pragma unroll
    for (int j = 0; j < 10; j++) {
      float4 v = src[j];
      wc[j*4+0] = v.x; wc[j*4+1] = v.y; wc[j*4+2] = v.z; wc[j*4+3] = v.w;
    }
  }
  const int row_base = (blockIdx.x * 4 + wid) * 4;
  #pragma unroll 1
  for (int r = 0; r < 4; r++) {
    const int row = row_base + r;                       // 0..8191 = b*T+t
    const float4* yr = (const float4*)(y + (size_t)row * C_ + lane * 8);
    float4 a = yr[0], b4 = yr[1];
    float s0 = 0.f, s1 = 0.f, s2 = 0.f, s3 = 0.f, s4 = 0.f;
    float e[8] = {a.x, a.y, a.z, a.w, b4.x, b4.y, b4.z, b4.w};
    #pragma unroll
    for (int j = 0; j < 8; j++) {
      s0 = fmaf(e[j], wc[j*5+0], s0);
      s1 = fmaf(e[j], wc[j*5+1], s1);
      s2 = fmaf(e[j], wc[j*5+2], s2);
      s3 = fmaf(e[j], wc[j*5+3], s3);
      s4 = fmaf(e[j], wc[j*5+4], s4);
    }
    #pragma unroll
    for (int off = 1; off < 64; off <<= 1) {
      s0 += __shfl_xor(s0, off); s1 += __shfl_xor(s1, off);
      s2 += __shfl_xor(s2, off); s3 += __shfl_xor(s3, off);
      s4 += __shfl_xor(s4, off);
    }
    float myv = (lane == 0) ? s0 : (lane == 1) ? s1 : (lane == 2) ? s2
              : (lane == 3) ? s3 : (lane == 4) ? s4 : 0.f;
    if (lane < 8) ycp[(size_t)row * 8 + lane] = __float2bfloat16(myv);
  }
}

// ---- k_bm: bm_bf = bf16(y @ W_proj2)  (8192x512)@(512x128) ----------------
// 512 threads, 32-row tile, grid 256; W loads coalesced + L1-cached.
__global__ __launch_bounds__(512) void k_bm(const float* __restrict__ y,
                                            const float* __restrict__ W,
                                            __hip_bfloat16* __restrict__ bmb) {
  __shared__ __align__(16) float ys[32 * 64];
  const int tid = threadIdx.x;
  const int row0 = blockIdx.x * 32;
  const int tn = tid & 127;
  const int tm = tid >> 7;  // 0..3 -> 8 rows each
  float acc[8];
  #pragma unroll
  for (int r = 0; r < 8; r++) acc[r] = 0.f;
  for (int cc = 0; cc < C_; cc += 64) {
    __syncthreads();
    {
      int r = tid >> 4, c4 = tid & 15;
      *(float4*)&ys[r*64 + c4*4] =
          *(const float4*)&y[(size_t)(row0 + r) * C_ + cc + c4*4];
    }
    __syncthreads();
    #pragma unroll
    for (int c4 = 0; c4 < 16; c4++) {
      const int c = cc + c4*4;
      const float w0 = W[(size_t)(c+0)*MB_ + tn], w1 = W[(size_t)(c+1)*MB_ + tn],
                  w2 = W[(size_t)(c+2)*MB_ + tn], w3 = W[(size_t)(c+3)*MB_ + tn];
      #pragma unroll
      for (int r = 0; r < 8; r++) {
        float4 v = *(float4*)&ys[(tm*8 + r)*64 + c4*4];
        acc[r] = fmaf(v.x, w0, fmaf(v.y, w1, fmaf(v.z, w2, fmaf(v.w, w3, acc[r]))));
      }
    }
  }
  #pragma unroll
  for (int r = 0; r < 8; r++)
    bmb[(size_t)(row0 + tm*8 + r) * MB_ + tn] = __float2bfloat16(acc[r]);
}

// ---- k_mid: wave-per-t, register-resident weights, readlane broadcasts ----
__global__ __launch_bounds__(256, 2) void k_mid(
    const __hip_bfloat16* __restrict__ ycp,   // [B][T][8]
    const __hip_bfloat16* __restrict__ bmb,   // [B][T][MB]
    const float* __restrict__ WB,             // [P][PS][CS]
    const float* __restrict__ Wbias,          // [P]
    const float* __restrict__ Wps1,           // [P][P]
    const int* __restrict__ patches,          // [T][P][PS]
    const int* __restrict__ pproj,            // [T][P]
    float* __restrict__ obm)                  // [B][T][MB]
{
  const int lane = threadIdx.x & 63;
  const int wid  = threadIdx.x >> 6;
  const int gw   = blockIdx.x * 4 + wid;      // 0..2047

  // persistent per-lane state: WB row (80), bias, Wps1 column (64)
  float wb[80];
  {
    const float4* src = (const float4*)(WB + lane * 80);
    #pragma unroll
    for (int j = 0; j < 20; j++) {
      float4 v = src[j];
      wb[j*4+0] = v.x; wb[j*4+1] = v.y; wb[j*4+2] = v.z; wb[j*4+3] = v.w;
    }
  }
  const float bias = Wbias[lane];
  float wcol[64];
  #pragma unroll
  for (int p = 0; p < 64; p++) wcol[p] = Wps1[p * 64 + lane];

  #pragma unroll 1
  for (int tt = 0; tt < 2; tt++) {
    const int t = gw * 2 + tt;                // 0..4095
    int idx[16];
    {
      const int4* psrc = (const int4*)(patches + (size_t)t * P_ * PS_ + lane * PS_);
      #pragma unroll
      for (int j = 0; j < 4; j++) {
        int4 v = psrc[j];
        idx[j*4+0] = v.x; idx[j*4+1] = v.y; idx[j*4+2] = v.z; idx[j*4+3] = v.w;
      }
    }
    const int pp = pproj[(size_t)t * P_ + lane];

    #pragma unroll 1
    for (int b = 0; b < B_; b++) {
      const __hip_bfloat16* yb = ycp + (size_t)b * T_ * 8;
      // res: gather 16 padded yc rows, dot with register WB row
      float sum = bias;
      #pragma unroll
      for (int s = 0; s < 16; s++) {
        uint4 g = *(const uint4*)(yb + (size_t)idx[s] * 8);
        sum = fmaf(bf_lo(g.x), wb[s*5+0], sum);
        sum = fmaf(bf_hi(g.x), wb[s*5+1], sum);
        sum = fmaf(bf_lo(g.y), wb[s*5+2], sum);
        sum = fmaf(bf_hi(g.y), wb[s*5+3], sum);
        sum = fmaf(bf_lo(g.z), wb[s*5+4], sum);
      }
      // mix[lane] = sum_p res[p] * Wps1[p][lane] via readlane broadcast
      float mix = 0.f;
      #pragma unroll
      for (int p = 0; p < 64; p++)
        mix = fmaf(rdlane_f(sum, p), wcol[p], mix);
      // out[m]: lane handles m = 2*lane, 2*lane+1
      const __hip_bfloat16* bb = bmb + (size_t)b * T_ * MB_;
      float ox = 0.f, oy = 0.f;
      #pragma unroll
      for (int p = 0; p < 64; p++) {
        const float mp = rdlane_f(mix, p);
        const int row = __builtin_amdgcn_readlane(pp, p);
        unsigned v = *(const unsigned*)(bb + (size_t)row * MB_ + lane * 2);
        ox = fmaf(bf_lo(v), mp, ox);
        oy = fmaf(bf_hi(v), mp, oy);
      }
      float2 o2 = make_float2(ox, oy);
      *(float2*)(obm + ((size_t)b * T_ + t) * MB_ + lane * 2) = o2;
    }
  }
}

// ---- k_final: out = obm @ W_FINAL  (8192x128)@(128x128) -------------------
__global__ __launch_bounds__(512) void k_final(const float* __restrict__ obm,
                                               const float* __restrict__ WF,
                                               float* __restrict__ outp) {
  __shared__ __align__(16) float os[32 * MB_];  // 16KB
  const int tid = threadIdx.x;
  const int row0 = blockIdx.x * 32;
  for (int j = tid; j < 32 * MB_ / 4; j += 512)
    ((float4*)os)[j] = ((const float4*)(obm + (size_t)row0 * MB_))[j];
  __syncthreads();
  const int tn = tid & 127, tm = tid >> 7;
  float acc[8];
  #pragma unroll
  for (int r = 0; r < 8; r++) acc[r] = 0.f;
  #pragma unroll
  for (int m4 = 0; m4 < MB_ / 4; m4++) {
    const int m = m4 * 4;
    const float w0 = WF[(size_t)(m+0)*FD_ + tn], w1 = WF[(size_t)(m+1)*FD_ + tn],
                w2 = WF[(size_t)(m+2)*FD_ + tn], w3 = WF[(size_t)(m+3)*FD_ + tn];
    #pragma unroll
    for (int r = 0; r < 8; r++) {
      float4 v = *(float4*)&os[(tm*8 + r)*MB_ + m];
      acc[r] = fmaf(v.x, w0, fmaf(v.y, w1, fmaf(v.z, w2, fmaf(v.w, w3, acc[r]))));
    }
  }
  #pragma unroll
  for (int r = 0; r < 8; r++)
    outp[(size_t)(row0 + tm*8 + r) * FD_ + tn] = acc[r];
}

extern "C" void kernel_launch(void* const* d_in, const int* in_sizes, int n_in,
                              void* d_out, int out_size, void* d_ws, size_t ws_size,
                              hipStream_t stream) {
  const float* y     = (const float*)d_in[0];
  const float* WB    = (const float*)d_in[1];
  const float* Wbias = (const float*)d_in[2];
  const float* Wp2   = (const float*)d_in[3];
  const float* Wpc   = (const float*)d_in[4];
  const float* Wps1  = (const float*)d_in[5];
  const float* WF    = (const float*)d_in[6];
  const int* patches = (const int*)d_in[7];
  const int* pproj   = (const int*)d_in[8];
  float* out = (float*)d_out;

  char* ws = (char*)d_ws;
  float* obm          = (float*)(ws);                        // 4 MB
  __hip_bfloat16* bmb = (__hip_bfloat16*)(ws + 4194304);     // 2 MB
  __hip_bfloat16* ycp = (__hip_bfloat16*)(ws + 6291456);     // 128 KB

  k_prep <<<dim3(512), dim3(256), 0, stream>>>(y, Wpc, ycp);
  k_bm   <<<dim3(256), dim3(512), 0, stream>>>(y, Wp2, bmb);
  k_mid  <<<dim3(512), dim3(256), 0, stream>>>(ycp, bmb, WB, Wbias, Wps1,
                                               patches, pproj, obm);
  k_final<<<dim3(256), dim3(512), 0, stream>>>(obm, WF, out);
}

// Round 3
// 151.115 us; speedup vs baseline: 1.8889x; 1.2174x over previous
//
#include <hip/hip_runtime.h>
#include <hip/hip_bf16.h>

#define B_ 2
#define T_ 4096
#define C_ 512
#define P_ 64
#define PS_ 16
#define CS_ 5
#define MB_ 128
#define FD_ 128

using f32x4 = __attribute__((ext_vector_type(4))) float;
using s16x8 = __attribute__((ext_vector_type(8))) short;

static __device__ __forceinline__ float bf_lo(unsigned u) {
  return __uint_as_float(u << 16);
}
static __device__ __forceinline__ float bf_hi(unsigned u) {
  return __uint_as_float(u & 0xffff0000u);
}
static __device__ __forceinline__ float rdlane_f(float v, int p) {
  return __uint_as_float((unsigned)__builtin_amdgcn_readlane((int)__float_as_uint(v), p));
}
// RNE float -> bf16 bits
static __device__ __forceinline__ ushort bf16u(float f) {
  unsigned x = __float_as_uint(f);
  unsigned r = (x + 0x7fffu + ((x >> 16) & 1u)) >> 16;
  return (ushort)r;
}

// ---- k_cvt: ybf = bf16(y); ycp[row][8] = bf16(y @ W_proj_comp) ------------
__global__ __launch_bounds__(256) void k_cvt(const float* __restrict__ y,
                                             const float* __restrict__ Wc,
                                             ushort* __restrict__ ybf,
                                             ushort* __restrict__ ycp) {
  const int lane = threadIdx.x & 63;
  const int wid  = threadIdx.x >> 6;
  float wc[40];
  {
    const float4* src = (const float4*)(Wc + lane * 40);
    #pragma unroll
    for (int j = 0; j < 10; j++) {
      float4 v = src[j];
      wc[j*4+0] = v.x; wc[j*4+1] = v.y; wc[j*4+2] = v.z; wc[j*4+3] = v.w;
    }
  }
  const int row_base = (blockIdx.x * 4 + wid) * 8;
  #pragma unroll 2
  for (int r = 0; r < 8; r++) {
    const int row = row_base + r;                       // 0..8191 = b*T+t
    const float4* yr = (const float4*)(y + (size_t)row * C_ + lane * 8);
    float4 a = yr[0], b4 = yr[1];
    float e[8] = {a.x, a.y, a.z, a.w, b4.x, b4.y, b4.z, b4.w};
    // bf16 copy of the row
    union { ushort us[8]; uint4 q; } pk;
    #pragma unroll
    for (int j = 0; j < 8; j++) pk.us[j] = bf16u(e[j]);
    *(uint4*)(ybf + (size_t)row * C_ + lane * 8) = pk.q;
    // yc row (5 dots, wave-reduced)
    float s0 = 0.f, s1 = 0.f, s2 = 0.f, s3 = 0.f, s4 = 0.f;
    #pragma unroll
    for (int j = 0; j < 8; j++) {
      s0 = fmaf(e[j], wc[j*5+0], s0);
      s1 = fmaf(e[j], wc[j*5+1], s1);
      s2 = fmaf(e[j], wc[j*5+2], s2);
      s3 = fmaf(e[j], wc[j*5+3], s3);
      s4 = fmaf(e[j], wc[j*5+4], s4);
    }
    #pragma unroll
    for (int off = 1; off < 64; off <<= 1) {
      s0 += __shfl_xor(s0, off); s1 += __shfl_xor(s1, off);
      s2 += __shfl_xor(s2, off); s3 += __shfl_xor(s3, off);
      s4 += __shfl_xor(s4, off);
    }
    float myv = (lane == 0) ? s0 : (lane == 1) ? s1 : (lane == 2) ? s2
              : (lane == 3) ? s3 : (lane == 4) ? s4 : 0.f;
    if (lane < 8) ycp[(size_t)row * 8 + lane] = bf16u(myv);
  }
}

// ---- k_cvtW: Wp2T[128][512] = bf16(Wp2^T); WFT[128][128] = bf16(WF^T) -----
__global__ __launch_bounds__(256) void k_cvtW(const float* __restrict__ Wp2,
                                              const float* __restrict__ WF,
                                              ushort* __restrict__ Wp2T,
                                              ushort* __restrict__ WFT) {
  const int id = blockIdx.x * 256 + threadIdx.x;
  if (id < C_ * MB_) {
    const int c = id >> 7, m = id & 127;
    Wp2T[(size_t)m * C_ + c] = bf16u(Wp2[id]);
  }
  const int id2 = id - C_ * MB_;
  if (id2 >= 0 && id2 < MB_ * FD_) {
    const int m = id2 >> 7, f = id2 & 127;
    WFT[(size_t)f * MB_ + m] = bf16u(WF[id2]);
  }
}

// ---- k_gemm: C[M][128] = A[M][K] @ Bt[128][K]^T  (bf16 MFMA, fp32 accum) ---
// BM=64, BN=128, BK=64; 4 waves 2x2, wave tile 32x64; XOR-swizzled LDS.
template<int KTOT, bool OUTBF>
__global__ __launch_bounds__(256) void k_gemm(const ushort* __restrict__ A,
                                              const ushort* __restrict__ Bt,
                                              void* __restrict__ Cout) {
  __shared__ __align__(16) char smem[(64 + 128) * 128];  // A 8KB @0, B 16KB @8192
  const int tid  = threadIdx.x;
  const int lane = tid & 63;
  const int wid  = tid >> 6;
  const int wm = wid >> 1, wn = wid & 1;
  const int rowA0 = blockIdx.x * 64;

  f32x4 acc[2][4];
  #pragma unroll
  for (int m = 0; m < 2; m++)
    #pragma unroll
    for (int n = 0; n < 4; n++) acc[m][n] = (f32x4){0.f, 0.f, 0.f, 0.f};

  for (int step = 0; step < KTOT / 64; step++) {
    const int kc = step * 64;
    // load staging data to regs (overlaps previous compute)
    uint4 ra[2], rb[4];
    #pragma unroll
    for (int i = 0; i < 2; i++) {
      const int slot = tid + i * 256, r = slot >> 3, sl = slot & 7;
      ra[i] = *(const uint4*)(A + (size_t)(rowA0 + r) * KTOT + kc + sl * 8);
    }
    #pragma unroll
    for (int i = 0; i < 4; i++) {
      const int slot = tid + i * 256, r = slot >> 3, sl = slot & 7;
      rb[i] = *(const uint4*)(Bt + (size_t)r * KTOT + kc + sl * 8);
    }
    __syncthreads();   // previous compute done before overwrite
    #pragma unroll
    for (int i = 0; i < 2; i++) {
      const int slot = tid + i * 256, r = slot >> 3, sl = slot & 7;
      *(uint4*)(smem + r * 128 + ((sl * 16) ^ ((r & 7) << 4))) = ra[i];
    }
    #pragma unroll
    for (int i = 0; i < 4; i++) {
      const int slot = tid + i * 256, r = slot >> 3, sl = slot & 7;
      *(uint4*)(smem + 8192 + r * 128 + ((sl * 16) ^ ((r & 7) << 4))) = rb[i];
    }
    __syncthreads();
    // compute: 2 MFMA-K slices of 32
    #pragma unroll
    for (int kk = 0; kk < 2; kk++) {
      const int cb = kk * 64 + (lane >> 4) * 16;
      s16x8 a[2], b[4];
      #pragma unroll
      for (int m = 0; m < 2; m++) {
        const int r = wm * 32 + m * 16 + (lane & 15);
        a[m] = *(const s16x8*)(smem + r * 128 + (cb ^ ((r & 7) << 4)));
      }
      #pragma unroll
      for (int n = 0; n < 4; n++) {
        const int rn = wn * 64 + n * 16 + (lane & 15);
        b[n] = *(const s16x8*)(smem + 8192 + rn * 128 + (cb ^ ((rn & 7) << 4)));
      }
      #pragma unroll
      for (int m = 0; m < 2; m++)
        #pragma unroll
        for (int n = 0; n < 4; n++)
          acc[m][n] = __builtin_amdgcn_mfma_f32_16x16x32_bf16(a[m], b[n], acc[m][n], 0, 0, 0);
    }
  }
  // epilogue: row=(lane>>4)*4+reg (M), col=lane&15 (N)
  #pragma unroll
  for (int m = 0; m < 2; m++) {
    #pragma unroll
    for (int n = 0; n < 4; n++) {
      #pragma unroll
      for (int reg = 0; reg < 4; reg++) {
        const int grow = rowA0 + wm * 32 + m * 16 + (lane >> 4) * 4 + reg;
        const int gcol = wn * 64 + n * 16 + (lane & 15);
        if (OUTBF)
          ((ushort*)Cout)[(size_t)grow * 128 + gcol] = bf16u(acc[m][n][reg]);
        else
          ((float*)Cout)[(size_t)grow * 128 + gcol] = acc[m][n][reg];
      }
    }
  }
}

// ---- k_mid: wave-per-t, register-resident weights, readlane broadcasts ----
__global__ __launch_bounds__(256, 2) void k_mid(
    const ushort* __restrict__ ycp,   // [B][T][8] bf16
    const ushort* __restrict__ bmb,   // [B][T][MB] bf16
    const float* __restrict__ WB,     // [P][PS][CS]
    const float* __restrict__ Wbias,  // [P]
    const float* __restrict__ Wps1,   // [P][P]
    const int* __restrict__ patches,  // [T][P][PS]
    const int* __restrict__ pproj,    // [T][P]
    ushort* __restrict__ obmb)        // [B][T][MB] bf16
{
  const int lane = threadIdx.x & 63;
  const int wid  = threadIdx.x >> 6;
  const int gw   = blockIdx.x * 4 + wid;      // 0..2047

  float wb[80];
  {
    const float4* src = (const float4*)(WB + lane * 80);
    #pragma unroll
    for (int j = 0; j < 20; j++) {
      float4 v = src[j];
      wb[j*4+0] = v.x; wb[j*4+1] = v.y; wb[j*4+2] = v.z; wb[j*4+3] = v.w;
    }
  }
  const float bias = Wbias[lane];
  float wcol[64];
  #pragma unroll
  for (int p = 0; p < 64; p++) wcol[p] = Wps1[p * 64 + lane];

  #pragma unroll 1
  for (int tt = 0; tt < 2; tt++) {
    const int t = gw * 2 + tt;                // 0..4095
    int idx[16];
    {
      const int4* psrc = (const int4*)(patches + (size_t)t * P_ * PS_ + lane * PS_);
      #pragma unroll
      for (int j = 0; j < 4; j++) {
        int4 v = psrc[j];
        idx[j*4+0] = v.x; idx[j*4+1] = v.y; idx[j*4+2] = v.z; idx[j*4+3] = v.w;
      }
    }
    const int pp = pproj[(size_t)t * P_ + lane];

    #pragma unroll 1
    for (int b = 0; b < B_; b++) {
      const ushort* yb = ycp + (size_t)b * T_ * 8;
      float sum = bias;
      #pragma unroll
      for (int s = 0; s < 16; s++) {
        uint4 g = *(const uint4*)(yb + (size_t)idx[s] * 8);
        sum = fmaf(bf_lo(g.x), wb[s*5+0], sum);
        sum = fmaf(bf_hi(g.x), wb[s*5+1], sum);
        sum = fmaf(bf_lo(g.y), wb[s*5+2], sum);
        sum = fmaf(bf_hi(g.y), wb[s*5+3], sum);
        sum = fmaf(bf_lo(g.z), wb[s*5+4], sum);
      }
      float mix = 0.f;
      #pragma unroll
      for (int p = 0; p < 64; p++)
        mix = fmaf(rdlane_f(sum, p), wcol[p], mix);
      const ushort* bb = bmb + (size_t)b * T_ * MB_;
      float ox = 0.f, oy = 0.f;
      #pragma unroll
      for (int p = 0; p < 64; p++) {
        const float mp = rdlane_f(mix, p);
        const int row = __builtin_amdgcn_readlane(pp, p);
        unsigned v = *(const unsigned*)(bb + (size_t)row * MB_ + lane * 2);
        ox = fmaf(bf_lo(v), mp, ox);
        oy = fmaf(bf_hi(v), mp, oy);
      }
      unsigned pkd = (unsigned)bf16u(ox) | ((unsigned)bf16u(oy) << 16);
      *(unsigned*)(obmb + ((size_t)b * T_ + t) * MB_ + lane * 2) = pkd;
    }
  }
}

extern "C" void kernel_launch(void* const* d_in, const int* in_sizes, int n_in,
                              void* d_out, int out_size, void* d_ws, size_t ws_size,
                              hipStream_t stream) {
  const float* y     = (const float*)d_in[0];
  const float* WB    = (const float*)d_in[1];
  const float* Wbias = (const float*)d_in[2];
  const float* Wp2   = (const float*)d_in[3];
  const float* Wpc   = (const float*)d_in[4];
  const float* Wps1  = (const float*)d_in[5];
  const float* WF    = (const float*)d_in[6];
  const int* patches = (const int*)d_in[7];
  const int* pproj   = (const int*)d_in[8];
  float* out = (float*)d_out;

  char* ws = (char*)d_ws;
  ushort* ybf  = (ushort*)(ws);                    // 8 MB   [8192][512]
  ushort* obmb = (ushort*)(ws);                    // 2 MB   (aliases ybf; ybf dead)
  ushort* bmb  = (ushort*)(ws + 8388608);          // 2 MB   [2][4096][128]
  ushort* ycp  = (ushort*)(ws + 10485760);         // 128 KB [2][4096][8]
  ushort* Wp2T = (ushort*)(ws + 10616832);         // 128 KB [128][512]
  ushort* WFT  = (ushort*)(ws + 10747904);         // 32 KB  [128][128]

  k_cvtW<<<dim3(320), dim3(256), 0, stream>>>(Wp2, WF, Wp2T, WFT);
  k_cvt <<<dim3(256), dim3(256), 0, stream>>>(y, Wpc, ybf, ycp);
  k_gemm<512, true> <<<dim3(128), dim3(256), 0, stream>>>(ybf, Wp2T, (void*)bmb);
  k_mid <<<dim3(512), dim3(256), 0, stream>>>(ycp, bmb, WB, Wbias, Wps1,
                                              patches, pproj, obmb);
  k_gemm<128, false><<<dim3(128), dim3(256), 0, stream>>>(obmb, WFT, (void*)out);
}